// Round 10
// baseline (2925.285 us; speedup 1.0000x reference)
//
#include <hip/hip_runtime.h>
#include <hip/hip_bf16.h>

typedef unsigned int uint;
typedef unsigned short ushort;

typedef short s16x8 __attribute__((ext_vector_type(8)));
typedef float f32x4 __attribute__((ext_vector_type(4)));
typedef uint  u32x4 __attribute__((ext_vector_type(4)));

#define NB 8
#define NT 1024
#define NV 8192
#define ND 768
#define NH 12
#define NL 6
#define NDH 64
#define NFF 3072
#define NTOK (NB*NT)

__device__ __forceinline__ ushort f2bf(float f) {
  uint x = __float_as_uint(f);
  x += 0x7FFFu + ((x >> 16) & 1u);
  return (ushort)(x >> 16);
}
__device__ __forceinline__ float bf2f(ushort u) {
  return __uint_as_float(((uint)u) << 16);
}

// XOR swizzle within a 64-ushort (128B) row: 16B chunk index ^= row&7 (attn LDS)
__device__ __forceinline__ int swz(int row, int col) {
  return row * 64 + ((((col >> 3) ^ row) & 7) << 3) + (col & 7);
}

// async global->LDS, 16B per lane, dest = wave-uniform base + lane*16
__device__ __forceinline__ void gload16(const ushort* g, ushort* l) {
  __builtin_amdgcn_global_load_lds(
      (const __attribute__((address_space(1))) void*)g,
      (__attribute__((address_space(3))) void*)l, 16, 0, 0);
}

// ---------------- embed ----------------
__global__ __launch_bounds__(192) void embed_kernel(
    const int* __restrict__ idx, const float* __restrict__ tok,
    const float* __restrict__ pos, float* __restrict__ x)
{
  int n = blockIdx.x, t = threadIdx.x;
  int token = idx[n];
  const float4* tp = (const float4*)(tok + (size_t)token * ND);
  const float4* pp = (const float4*)(pos + (size_t)(n & (NT - 1)) * ND);
  float4 a = tp[t], b = pp[t];
  float4 r; r.x = a.x + b.x; r.y = a.y + b.y; r.z = a.z + b.z; r.w = a.w + b.w;
  ((float4*)(x + (size_t)n * ND))[t] = r;
}

// ---------------- layernorm (f32 in -> bf16 out) ----------------
__global__ __launch_bounds__(256) void ln_kernel(
    const float* __restrict__ x, const float* __restrict__ g,
    const float* __restrict__ b, ushort* __restrict__ out)
{
  int row = blockIdx.x, tid = threadIdx.x;
  const float* xr = x + (size_t)row * ND;
  float v0 = xr[tid], v1 = xr[tid + 256], v2 = xr[tid + 512];
  float s = v0 + v1 + v2;
  float q = v0 * v0 + v1 * v1 + v2 * v2;
  #pragma unroll
  for (int d = 1; d < 64; d <<= 1) { s += __shfl_xor(s, d); q += __shfl_xor(q, d); }
  __shared__ float rs[4], rq[4];
  int w = tid >> 6;
  if ((tid & 63) == 0) { rs[w] = s; rq[w] = q; }
  __syncthreads();
  s = rs[0] + rs[1] + rs[2] + rs[3];
  q = rq[0] + rq[1] + rq[2] + rq[3];
  float mean = s * (1.0f / ND);
  float inv = rsqrtf(q * (1.0f / ND) - mean * mean + 1e-5f);
  ushort* orow = out + (size_t)row * ND;
  orow[tid]       = f2bf((v0 - mean) * inv * g[tid]       + b[tid]);
  orow[tid + 256] = f2bf((v1 - mean) * inv * g[tid + 256] + b[tid + 256]);
  orow[tid + 512] = f2bf((v2 - mean) * inv * g[tid + 512] + b[tid + 512]);
}

// ------- batched transpose + f32->bf16: out[(bi/HB)*sl + (bi%HB)*sh + c*R+r] = in[bi][r][c]
__global__ __launch_bounds__(256) void transp2(
    const float* __restrict__ in, ushort* __restrict__ out, int R, int C,
    int HB, size_t sh, size_t sl, int total)
{
  int o = blockIdx.x * 256 + threadIdx.x;
  if (o >= total) return;
  int rc = R * C;
  int bi = o / rc;
  int rem = o - bi * rc;
  int c = rem / R;
  int r = rem - c * R;
  out[(size_t)(bi / HB) * sl + (size_t)(bi % HB) * sh + rem] =
      f2bf(in[(size_t)bi * rc + (size_t)r * C + c]);
}

// ---------------- bf16 MFMA GEMM 128x128 (m97 structure + bank swizzle) ------
// OUT: 0 = none, 1 = bf16, 2 = f32.  LDS [128][32] linear; data swizzled:
// LDS(row, chunk) holds global(row, chunk ^ ((row>>1)&3)), chunk = 16B unit.
template<bool BIAS, bool RELU, bool RESID, int OUT>
__global__ __launch_bounds__(256) void gemm_bt(
    const ushort* __restrict__ A, const ushort* __restrict__ Bt,
    const float* __restrict__ bias, float* __restrict__ xres,
    void* __restrict__ outp, int M, int N, int K)
{
  __shared__ ushort As[4096];
  __shared__ ushort Bs[4096];
  const int tid = threadIdx.x;
  const int lane = tid & 63;
  const int w = tid >> 6;
  const int wr = w >> 1, wc = w & 1;
  const int lg = lane >> 4, li = lane & 15;
  const int m0 = blockIdx.y * 128, n0 = blockIdx.x * 128;

  const ushort* gA = &A[(size_t)(m0 + (tid >> 2)) * K + (((tid & 3) ^ ((tid >> 3) & 3)) << 3)];
  const ushort* gB = &Bt[(size_t)(n0 + (tid >> 2)) * K + (((tid & 3) ^ ((tid >> 3) & 3)) << 3)];
  const size_t rowK64 = (size_t)64 * K;
  ushort* lA0 = &As[w * 512];
  ushort* lA1 = &As[2048 + w * 512];
  ushort* lB0 = &Bs[w * 512];
  ushort* lB1 = &Bs[2048 + w * 512];

  f32x4 acc[4][4];
  #pragma unroll
  for (int i = 0; i < 4; ++i)
    #pragma unroll
    for (int j = 0; j < 4; ++j) { f32x4 z = {0.f,0.f,0.f,0.f}; acc[i][j] = z; }

  for (int kk = 0; kk < K; kk += 32) {
    __syncthreads();
    gload16(gA + kk, lA0);
    gload16(gA + kk + rowK64, lA1);
    gload16(gB + kk, lB0);
    gload16(gB + kk + rowK64, lB1);
    __syncthreads();
    s16x8 af[4], bfr[4];
    #pragma unroll
    for (int i = 0; i < 4; ++i) {
      int ra = wr * 64 + i * 16 + li;
      int rb = wc * 64 + i * 16 + li;
      int ca = ((lg ^ (li >> 1)) & 3) << 3;
      af[i]  = *(const s16x8*)&As[(ra << 5) + ca];
      bfr[i] = *(const s16x8*)&Bs[(rb << 5) + ca];
    }
    #pragma unroll
    for (int i = 0; i < 4; ++i)
      #pragma unroll
      for (int j = 0; j < 4; ++j)
        acc[i][j] = __builtin_amdgcn_mfma_f32_16x16x32_bf16(af[i], bfr[j], acc[i][j], 0, 0, 0);
  }

  #pragma unroll
  for (int i = 0; i < 4; ++i) {
    #pragma unroll
    for (int j = 0; j < 4; ++j) {
      int row0 = m0 + wr * 64 + i * 16 + lg * 4;
      int col  = n0 + wc * 64 + j * 16 + li;
      float bv = BIAS ? bias[col] : 0.f;
      #pragma unroll
      for (int ii = 0; ii < 4; ++ii) {
        float val = acc[i][j][ii] + bv;
        if (RELU) val = fmaxf(val, 0.f);
        size_t off = (size_t)(row0 + ii) * N + col;
        if (RESID) { val += xres[off]; xres[off] = val; }
        if (OUT == 1) ((ushort*)outp)[off] = f2bf(val);
        if (OUT == 2) ((float*)outp)[off] = val;
      }
    }
  }
}

// ---------------- bf16 MFMA GEMM 256x256, 4-buffer distance-3 pipeline -------
// 512 threads, 8 waves (2Mx4N), per-wave out 128x64, BK=32.
// Buf cycle: while reading buf kt&3, stage tile kt+3 into buf (kt+3)&3, which
// holds tile kt-1 (fully consumed at the previous end-of-step barrier) ->
// writes and reads are disjoint; ONE barrier per K-step. Counted vmcnt(8)
// guarantees tile kt+1 landed before the barrier. Requires nt = K/32 >= 3.
template<bool BIAS, bool RELU, int OUT>
__global__ __launch_bounds__(512, 1) void gemm256(
    const ushort* __restrict__ A, const ushort* __restrict__ Bt,
    const float* __restrict__ bias, void* __restrict__ outp,
    int M, int N, int K)
{
  __shared__ ushort As[4][8192];   // [buf][256 rows][32 cols]
  __shared__ ushort Bs[4][8192];
  const int tid = threadIdx.x;
  const int lane = tid & 63;
  const int w = tid >> 6;
  const int wr = w >> 2, wc = w & 3;
  const int lg = lane >> 4, li = lane & 15;
  const int cw = ((lg ^ (li >> 1)) & 3) << 3;   // swizzled chunk offset (reads)

  // XCD-aware bijective block swizzle (all grids have nwg % 8 == 0)
  const int gx = gridDim.x;
  int nwg = gx * gridDim.y;
  int bid = blockIdx.y * gx + blockIdx.x;
  int swb = (bid & 7) * (nwg >> 3) + (bid >> 3);
  const int m0 = (swb / gx) * 256, n0 = (swb % gx) * 256;

  const ushort* pA = A + (size_t)(m0 + w * 16 + (lane >> 2)) * K
                       + (((lane & 3) ^ ((lane >> 3) & 3)) << 3);
  const ushort* pB = Bt + (size_t)(n0 + w * 16 + (lane >> 2)) * K
                        + (((lane & 3) ^ ((lane >> 3) & 3)) << 3);
  const size_t r128 = (size_t)128 * K;

  f32x4 acc[8][4];
  #pragma unroll
  for (int m = 0; m < 8; ++m)
    #pragma unroll
    for (int n = 0; n < 4; ++n) { f32x4 z = {0.f,0.f,0.f,0.f}; acc[m][n] = z; }

  const int nt = K >> 5;

  #define STAGE256(t_) do {                                   \
    int kk_ = (t_) << 5;                                      \
    ushort* dA_ = &As[(t_) & 3][w * 512];                     \
    ushort* dB_ = &Bs[(t_) & 3][w * 512];                     \
    gload16(pA + kk_, dA_);                                   \
    gload16(pA + kk_ + r128, dA_ + 4096);                     \
    gload16(pB + kk_, dB_);                                   \
    gload16(pB + kk_ + r128, dB_ + 4096);                     \
  } while (0)

  #define BAR()   asm volatile("s_barrier" ::: "memory")
  #define VM8()   asm volatile("s_waitcnt vmcnt(8)" ::: "memory")
  #define VM4()   asm volatile("s_waitcnt vmcnt(4)" ::: "memory")
  #define VM0()   asm volatile("s_waitcnt vmcnt(0)" ::: "memory")

  STAGE256(0); STAGE256(1); STAGE256(2);
  VM8();                    // my tile-0 loads landed
  BAR();                    // all waves' tile-0 loads landed -> visible

  for (int kt = 0; kt < nt; ++kt) {
    if (kt + 3 < nt) STAGE256(kt + 3);     // into buf holding dead tile kt-1
    const ushort* as_ = As[kt & 3];
    const ushort* bs_ = Bs[kt & 3];
    s16x8 af[8], bfr[4];
    #pragma unroll
    for (int m = 0; m < 8; ++m) {
      int row = wr * 128 + m * 16 + li;
      af[m] = *(const s16x8*)&as_[(row << 5) + cw];
    }
    #pragma unroll
    for (int n = 0; n < 4; ++n) {
      int row = wc * 64 + n * 16 + li;
      bfr[n] = *(const s16x8*)&bs_[(row << 5) + cw];
    }
    __builtin_amdgcn_s_setprio(1);
    #pragma unroll
    for (int m = 0; m < 8; ++m)
      #pragma unroll
      for (int n = 0; n < 4; ++n)
        acc[m][n] = __builtin_amdgcn_mfma_f32_16x16x32_bf16(af[m], bfr[n], acc[m][n], 0, 0, 0);
    __builtin_amdgcn_s_setprio(0);
    // ensure tile kt+1 (oldest in flight) has landed, then sync
    if (kt + 3 < nt)      VM8();
    else if (kt + 2 < nt) VM4();
    else if (kt + 1 < nt) VM0();
    BAR();
  }

  #undef STAGE256
  #undef BAR
  #undef VM8
  #undef VM4
  #undef VM0

  #pragma unroll
  for (int m = 0; m < 8; ++m) {
    #pragma unroll
    for (int n = 0; n < 4; ++n) {
      int row0 = m0 + wr * 128 + m * 16 + lg * 4;
      int col  = n0 + wc * 64 + n * 16 + li;
      float bv = BIAS ? bias[col] : 0.f;
      #pragma unroll
      for (int ii = 0; ii < 4; ++ii) {
        float val = acc[m][n][ii] + bv;
        if (RELU) val = fmaxf(val, 0.f);
        size_t off = (size_t)(row0 + ii) * N + col;
        if (OUT == 1) ((ushort*)outp)[off] = f2bf(val);
        if (OUT == 2) ((float*)outp)[off] = val;
      }
    }
  }
}

// ---------------- MFMA causal flash attention ----------------
// qkv: [NTOK][2304] bf16 (q: col h*64, k: 768+h*64, v: 1536+h*64). o: [NTOK][768].
__global__ __launch_bounds__(256) void attn_kernel(
    const ushort* __restrict__ qkv, ushort* __restrict__ o)
{
  __shared__ ushort Ks[64 * 64];     // [key][dh], swizzled
  __shared__ ushort Vt[64 * 64];     // [dh][key], swizzled
  __shared__ ushort Ps[4][16 * 64];  // per-wave P [qrow][key], swizzled

  const int tid = threadIdx.x;
  const int lane = tid & 63;
  const int w = tid >> 6;
  const int lg = lane >> 4;
  const int li = lane & 15;

  int bid = blockIdx.x;
  const int qt = bid & 15;
  const int h = (bid >> 4) % NH;
  const int b = bid / (16 * NH);
  const int q0 = qt * 64 + w * 16;
  const size_t nbase = (size_t)b * NT;
  const int hq = h * NDH;
  const int hk = ND + h * NDH;
  const int hv = 2 * ND + h * NDH;

  s16x8 aq[2];
  #pragma unroll
  for (int c = 0; c < 2; ++c)
    aq[c] = *(const s16x8*)&qkv[(nbase + q0 + li) * (3 * ND) + hq + c * 32 + lg * 8];

  float m_r[4], l_r[4];
  f32x4 oacc[4];
  #pragma unroll
  for (int i = 0; i < 4; ++i) { m_r[i] = -1e30f; l_r[i] = 0.f; }
  #pragma unroll
  for (int f = 0; f < 4; ++f) { f32x4 z = {0.f,0.f,0.f,0.f}; oacc[f] = z; }

  const float scale = 0.036084391824351615f;  // 768^-0.5 (reference uses D, not DH)

  const int nkc = qt + 1;
  for (int kc = 0; kc < nkc; ++kc) {
    #pragma unroll
    for (int p = 0; p < 2; ++p) {
      int id2 = p * 256 + tid;
      int key = id2 >> 3, c8 = (id2 & 7) * 8;
      size_t rb = (nbase + kc * 64 + key) * (size_t)(3 * ND);
      u32x4 kvv = *(const u32x4*)&qkv[rb + hk + c8];
      *(u32x4*)&Ks[swz(key, c8)] = kvv;
      u32x4 vvv = *(const u32x4*)&qkv[rb + hv + c8];
      ushort* vp = (ushort*)&vvv;
      #pragma unroll
      for (int j = 0; j < 8; ++j) Vt[swz(c8 + j, key)] = vp[j];
    }
    __syncthreads();
    f32x4 s[4];
    #pragma unroll
    for (int kt = 0; kt < 4; ++kt) {
      f32x4 z = {0.f,0.f,0.f,0.f}; s[kt] = z;
      #pragma unroll
      for (int c = 0; c < 2; ++c) {
        s16x8 bk = *(const s16x8*)&Ks[swz(kt * 16 + li, c * 32 + lg * 8)];
        s[kt] = __builtin_amdgcn_mfma_f32_16x16x32_bf16(aq[c], bk, s[kt], 0, 0, 0);
      }
    }
    #pragma unroll
    for (int i = 0; i < 4; ++i) {
      int row = q0 + lg * 4 + i;
      float sv[4]; float mx = -1e30f;
      #pragma unroll
      for (int kt = 0; kt < 4; ++kt) {
        int key = kc * 64 + kt * 16 + li;
        float t = s[kt][i] * scale;
        t = (key <= row) ? t : -1e30f;
        sv[kt] = t; mx = fmaxf(mx, t);
      }
      #pragma unroll
      for (int d = 1; d < 16; d <<= 1) mx = fmaxf(mx, __shfl_xor(mx, d));
      float mnew = fmaxf(m_r[i], mx);
      float corr = __expf(m_r[i] - mnew);
      float ps = 0.f;
      #pragma unroll
      for (int kt = 0; kt < 4; ++kt) {
        float pe = __expf(sv[kt] - mnew);
        ps += pe;
        Ps[w][swz(lg * 4 + i, kt * 16 + li)] = f2bf(pe);
      }
      #pragma unroll
      for (int d = 1; d < 16; d <<= 1) ps += __shfl_xor(ps, d);
      l_r[i] = l_r[i] * corr + ps;
      m_r[i] = mnew;
      #pragma unroll
      for (int f = 0; f < 4; ++f) oacc[f][i] *= corr;
    }
    #pragma unroll
    for (int f = 0; f < 4; ++f) {
      #pragma unroll
      for (int c = 0; c < 2; ++c) {
        s16x8 ap = *(const s16x8*)&Ps[w][swz(li, c * 32 + lg * 8)];
        s16x8 bv = *(const s16x8*)&Vt[swz(f * 16 + li, c * 32 + lg * 8)];
        oacc[f] = __builtin_amdgcn_mfma_f32_16x16x32_bf16(ap, bv, oacc[f], 0, 0, 0);
      }
    }
    __syncthreads();
  }
  #pragma unroll
  for (int f = 0; f < 4; ++f)
    #pragma unroll
    for (int i = 0; i < 4; ++i) {
      float val = oacc[f][i] / l_r[i];
      o[(nbase + q0 + lg * 4 + i) * ND + h * NDH + f * 16 + li] = f2bf(val);
    }
}

// ---------------- loss (f32 logits), deterministic two-stage ----------------
__global__ __launch_bounds__(256) void loss_row(
    const float* __restrict__ logits, const int* __restrict__ targets,
    float* __restrict__ rowloss)
{
  int row = blockIdx.x, tid = threadIdx.x;
  const float* lr = logits + (size_t)row * NV;
  const float4* l4 = (const float4*)lr;
  float vals[32];
  float mx = -1e30f;
  #pragma unroll
  for (int p = 0; p < 8; ++p) {
    float4 t = l4[p * 256 + tid];
    vals[p*4+0] = t.x; vals[p*4+1] = t.y; vals[p*4+2] = t.z; vals[p*4+3] = t.w;
    mx = fmaxf(mx, fmaxf(fmaxf(t.x, t.y), fmaxf(t.z, t.w)));
  }
  #pragma unroll
  for (int d = 1; d < 64; d <<= 1) mx = fmaxf(mx, __shfl_xor(mx, d));
  __shared__ float red[4], red2[4];
  int w = tid >> 6, lane = tid & 63;
  if (lane == 0) red[w] = mx;
  __syncthreads();
  mx = fmaxf(fmaxf(red[0], red[1]), fmaxf(red[2], red[3]));
  float sm = 0.f;
  #pragma unroll
  for (int i = 0; i < 32; ++i) sm += __expf(vals[i] - mx);
  #pragma unroll
  for (int d = 1; d < 64; d <<= 1) sm += __shfl_xor(sm, d);
  if (lane == 0) red2[w] = sm;
  __syncthreads();
  if (tid == 0) {
    float total = red2[0] + red2[1] + red2[2] + red2[3];
    float lse = mx + __logf(total);
    rowloss[row] = lse - lr[targets[row]];
  }
}

__global__ __launch_bounds__(256) void loss_reduce(
    const float* __restrict__ rowloss, float* __restrict__ out_loss)
{
  int tid = threadIdx.x;
  float s = 0.f;
  #pragma unroll
  for (int i = 0; i < 32; ++i) s += rowloss[tid + i * 256];
  #pragma unroll
  for (int d = 1; d < 64; d <<= 1) s += __shfl_xor(s, d);
  __shared__ float red[4];
  int w = tid >> 6, lane = tid & 63;
  if (lane == 0) red[w] = s;
  __syncthreads();
  if (tid == 0) {
    float total = red[0] + red[1] + red[2] + red[3];
    out_loss[0] = total * (1.0f / NTOK);
  }
}

// ---------------- launch ----------------
extern "C" void kernel_launch(void* const* d_in, const int* in_sizes, int n_in,
                              void* d_out, int out_size, void* d_ws, size_t ws_size,
                              hipStream_t stream)
{
  const int*   idx     = (const int*)d_in[0];
  const int*   targets = (const int*)d_in[1];
  const float* tok     = (const float*)d_in[2];
  const float* pos     = (const float*)d_in[3];
  const float* ln1g    = (const float*)d_in[4];
  const float* ln1b    = (const float*)d_in[5];
  const float* Wq      = (const float*)d_in[6];
  const float* Wk      = (const float*)d_in[7];
  const float* Wv      = (const float*)d_in[8];
  const float* Wp      = (const float*)d_in[9];
  const float* bp      = (const float*)d_in[10];
  const float* ln2g    = (const float*)d_in[11];
  const float* ln2b    = (const float*)d_in[12];
  const float* W1      = (const float*)d_in[13];
  const float* b1      = (const float*)d_in[14];
  const float* W2      = (const float*)d_in[15];
  const float* b2      = (const float*)d_in[16];
  const float* lnfg    = (const float*)d_in[17];
  const float* lnfb    = (const float*)d_in[18];
  const float* Wlm     = (const float*)d_in[19];
  const float* blm     = (const float*)d_in[20];

  // d_out (f32, 268,435,460 B) doubles as scratch; all dead before final GEMM.
  char* ob = (char*)d_out;
  float*  x    = (float*)ob;
  ushort* qkvb = (ushort*)(ob + 25165824);
  ushort* mid  = (ushort*)(ob + 25165824);
  ushort* qkvT = (ushort*)(ob + 75497472);                  // 6 x [2304][768]
  ushort* wpT  = (ushort*)(ob + 75497472 + 21233664);       // 6 x [768][768]
  ushort* w1T  = (ushort*)(ob + 75497472 + 28311552);       // 6 x [3072][768]
  ushort* w2T  = (ushort*)(ob + 75497472 + 56623104);       // 6 x [768][3072]
  float* logits = (float*)d_out;

  char* ws = (char*)d_ws;
  size_t off = 0;
  auto alloc = [&](size_t bytes) -> void* {
    void* p = ws + off; off += (bytes + 255) & ~(size_t)255; return p;
  };
  ushort* h    = (ushort*)alloc((size_t)NTOK * ND * 2);     // ln out / attn out
  ushort* wlmT = (ushort*)alloc((size_t)ND * NV * 2);       // read during logits GEMM
  float*  rowloss = (float*)alloc((size_t)NTOK * 4);

  embed_kernel<<<NTOK, 192, 0, stream>>>(idx, tok, pos, x);

  const size_t LQKV = (size_t)2304 * ND;
  {
    int tq = NL * NH * ND * NDH;
    transp2<<<(tq + 255) / 256, 256, 0, stream>>>(Wq, qkvT,                 ND, NDH, NH, (size_t)NDH * ND, LQKV, tq);
    transp2<<<(tq + 255) / 256, 256, 0, stream>>>(Wk, qkvT + (size_t)ND*ND, ND, NDH, NH, (size_t)NDH * ND, LQKV, tq);
    transp2<<<(tq + 255) / 256, 256, 0, stream>>>(Wv, qkvT + (size_t)2*ND*ND, ND, NDH, NH, (size_t)NDH * ND, LQKV, tq);
    int tp = NL * ND * ND;
    transp2<<<(tp + 255) / 256, 256, 0, stream>>>(Wp, wpT, ND, ND, 1, 0, (size_t)ND * ND, tp);
    int tf = NL * ND * NFF;
    transp2<<<(tf + 255) / 256, 256, 0, stream>>>(W1, w1T, ND, NFF, 1, 0, (size_t)ND * NFF, tf);
    transp2<<<(tf + 255) / 256, 256, 0, stream>>>(W2, w2T, NFF, ND, 1, 0, (size_t)ND * NFF, tf);
    int tl = ND * NV;
    transp2<<<(tl + 255) / 256, 256, 0, stream>>>(Wlm, wlmT, ND, NV, 1, 0, (size_t)ND * NV, tl);
  }

  dim3 gqkv(2304 / 256, NTOK / 256);   // 9 x 24 = 288
  dim3 gff1(NFF / 256, NTOK / 256);    // 12 x 24 = 384
  dim3 g768(ND / 128, NTOK / 128);     // 6 x 64 = 384
  dim3 glm(NV / 256, NTOK / 256);      // 32 x 24 = 1024

  for (int l = 0; l < NL; ++l) {
    ln_kernel<<<NTOK, 256, 0, stream>>>(x, ln1g + l * ND, ln1b + l * ND, h);
    gemm256<false,false,1><<<gqkv, 512, 0, stream>>>(h, qkvT + l * LQKV, nullptr, qkvb, NTOK, 2304, ND);
    attn_kernel<<<NB * NH * (NT / 64), 256, 0, stream>>>(qkvb, h);
    gemm_bt<true,false,true,0><<<g768, 256, 0, stream>>>(h, wpT + (size_t)l * ND * ND, bp + l * ND, x, nullptr, NTOK, ND, ND);
    ln_kernel<<<NTOK, 256, 0, stream>>>(x, ln2g + l * ND, ln2b + l * ND, h);
    gemm256<true,true,1><<<gff1, 512, 0, stream>>>(h, w1T + (size_t)l * ND * NFF, b1 + (size_t)l * NFF, mid, NTOK, NFF, ND);
    gemm_bt<true,false,true,0><<<g768, 256, 0, stream>>>(mid, w2T + (size_t)l * ND * NFF, b2 + l * ND, x, nullptr, NTOK, ND, NFF);
  }

  ln_kernel<<<NTOK, 256, 0, stream>>>(x, lnfg, lnfb, h);
  gemm256<true,false,2><<<glm, 512, 0, stream>>>(h, wlmT, blm, logits, NTOK, NV, ND);

  loss_row<<<NTOK, 256, 0, stream>>>(logits, targets, rowloss);
  loss_reduce<<<1, 256, 0, stream>>>(rowloss, logits + (size_t)NTOK * NV);
}

// Round 11
// 2669.015 us; speedup vs baseline: 1.0960x; 1.0960x over previous
//
#include <hip/hip_runtime.h>
#include <hip/hip_bf16.h>

typedef unsigned int uint;
typedef unsigned short ushort;

typedef short s16x8 __attribute__((ext_vector_type(8)));
typedef float f32x4 __attribute__((ext_vector_type(4)));
typedef uint  u32x4 __attribute__((ext_vector_type(4)));

#define NB 8
#define NT 1024
#define NV 8192
#define ND 768
#define NH 12
#define NL 6
#define NDH 64
#define NFF 3072
#define NTOK (NB*NT)

__device__ __forceinline__ ushort f2bf(float f) {
  uint x = __float_as_uint(f);
  x += 0x7FFFu + ((x >> 16) & 1u);
  return (ushort)(x >> 16);
}
__device__ __forceinline__ float bf2f(ushort u) {
  return __uint_as_float(((uint)u) << 16);
}

// XOR swizzle within a 64-ushort (128B) row: 16B chunk index ^= row&7 (attn LDS)
__device__ __forceinline__ int swz(int row, int col) {
  return row * 64 + ((((col >> 3) ^ row) & 7) << 3) + (col & 7);
}

// async global->LDS, 16B per lane, dest = wave-uniform base + lane*16
__device__ __forceinline__ void gload16(const ushort* g, ushort* l) {
  __builtin_amdgcn_global_load_lds(
      (const __attribute__((address_space(1))) void*)g,
      (__attribute__((address_space(3))) void*)l, 16, 0, 0);
}

// ---------------- embed ----------------
__global__ __launch_bounds__(192) void embed_kernel(
    const int* __restrict__ idx, const float* __restrict__ tok,
    const float* __restrict__ pos, float* __restrict__ x)
{
  int n = blockIdx.x, t = threadIdx.x;
  int token = idx[n];
  const float4* tp = (const float4*)(tok + (size_t)token * ND);
  const float4* pp = (const float4*)(pos + (size_t)(n & (NT - 1)) * ND);
  float4 a = tp[t], b = pp[t];
  float4 r; r.x = a.x + b.x; r.y = a.y + b.y; r.z = a.z + b.z; r.w = a.w + b.w;
  ((float4*)(x + (size_t)n * ND))[t] = r;
}

// ---------------- layernorm (f32 in -> bf16 out) ----------------
__global__ __launch_bounds__(256) void ln_kernel(
    const float* __restrict__ x, const float* __restrict__ g,
    const float* __restrict__ b, ushort* __restrict__ out)
{
  int row = blockIdx.x, tid = threadIdx.x;
  const float* xr = x + (size_t)row * ND;
  float v0 = xr[tid], v1 = xr[tid + 256], v2 = xr[tid + 512];
  float s = v0 + v1 + v2;
  float q = v0 * v0 + v1 * v1 + v2 * v2;
  #pragma unroll
  for (int d = 1; d < 64; d <<= 1) { s += __shfl_xor(s, d); q += __shfl_xor(q, d); }
  __shared__ float rs[4], rq[4];
  int w = tid >> 6;
  if ((tid & 63) == 0) { rs[w] = s; rq[w] = q; }
  __syncthreads();
  s = rs[0] + rs[1] + rs[2] + rs[3];
  q = rq[0] + rq[1] + rq[2] + rq[3];
  float mean = s * (1.0f / ND);
  float inv = rsqrtf(q * (1.0f / ND) - mean * mean + 1e-5f);
  ushort* orow = out + (size_t)row * ND;
  orow[tid]       = f2bf((v0 - mean) * inv * g[tid]       + b[tid]);
  orow[tid + 256] = f2bf((v1 - mean) * inv * g[tid + 256] + b[tid + 256]);
  orow[tid + 512] = f2bf((v2 - mean) * inv * g[tid + 512] + b[tid + 512]);
}

// ------- batched transpose + f32->bf16: out[(bi/HB)*sl + (bi%HB)*sh + c*R+r] = in[bi][r][c]
__global__ __launch_bounds__(256) void transp2(
    const float* __restrict__ in, ushort* __restrict__ out, int R, int C,
    int HB, size_t sh, size_t sl, int total)
{
  int o = blockIdx.x * 256 + threadIdx.x;
  if (o >= total) return;
  int rc = R * C;
  int bi = o / rc;
  int rem = o - bi * rc;
  int c = rem / R;
  int r = rem - c * R;
  out[(size_t)(bi / HB) * sl + (size_t)(bi % HB) * sh + rem] =
      f2bf(in[(size_t)bi * rc + (size_t)r * C + c]);
}

// ---------------- bf16 MFMA GEMM 128x128 (m97 structure + bank swizzle + XCD swizzle)
// OUT: 0 = none, 1 = bf16, 2 = f32.  LDS [128][32] linear; data swizzled:
// LDS(row, chunk) holds global(row, chunk ^ ((row>>1)&3)), chunk = 16B unit.
// Block remap: XCD k (= bid%8) gets a contiguous y-major chunk of tiles so its
// A panels stay L2-resident (T1/m204 bijective; requires nwg%8==0 — all grids ok).
template<bool BIAS, bool RELU, bool RESID, int OUT>
__global__ __launch_bounds__(256) void gemm_bt(
    const ushort* __restrict__ A, const ushort* __restrict__ Bt,
    const float* __restrict__ bias, float* __restrict__ xres,
    void* __restrict__ outp, int M, int N, int K)
{
  __shared__ ushort As[4096];
  __shared__ ushort Bs[4096];
  const int tid = threadIdx.x;
  const int lane = tid & 63;
  const int w = tid >> 6;
  const int wr = w >> 1, wc = w & 1;
  const int lg = lane >> 4, li = lane & 15;

  const int gx = gridDim.x;
  const int nwg = gx * gridDim.y;
  const int bid0 = blockIdx.y * gx + blockIdx.x;
  const int swb = (bid0 & 7) * (nwg >> 3) + (bid0 >> 3);
  const int m0 = (swb / gx) * 128, n0 = (swb % gx) * 128;

  const ushort* gA = &A[(size_t)(m0 + (tid >> 2)) * K + (((tid & 3) ^ ((tid >> 3) & 3)) << 3)];
  const ushort* gB = &Bt[(size_t)(n0 + (tid >> 2)) * K + (((tid & 3) ^ ((tid >> 3) & 3)) << 3)];
  const size_t rowK64 = (size_t)64 * K;
  ushort* lA0 = &As[w * 512];
  ushort* lA1 = &As[2048 + w * 512];
  ushort* lB0 = &Bs[w * 512];
  ushort* lB1 = &Bs[2048 + w * 512];

  f32x4 acc[4][4];
  #pragma unroll
  for (int i = 0; i < 4; ++i)
    #pragma unroll
    for (int j = 0; j < 4; ++j) { f32x4 z = {0.f,0.f,0.f,0.f}; acc[i][j] = z; }

  for (int kk = 0; kk < K; kk += 32) {
    __syncthreads();
    gload16(gA + kk, lA0);
    gload16(gA + kk + rowK64, lA1);
    gload16(gB + kk, lB0);
    gload16(gB + kk + rowK64, lB1);
    __syncthreads();
    s16x8 af[4], bfr[4];
    #pragma unroll
    for (int i = 0; i < 4; ++i) {
      int ra = wr * 64 + i * 16 + li;
      int rb = wc * 64 + i * 16 + li;
      int ca = ((lg ^ (li >> 1)) & 3) << 3;
      af[i]  = *(const s16x8*)&As[(ra << 5) + ca];
      bfr[i] = *(const s16x8*)&Bs[(rb << 5) + ca];
    }
    #pragma unroll
    for (int i = 0; i < 4; ++i)
      #pragma unroll
      for (int j = 0; j < 4; ++j)
        acc[i][j] = __builtin_amdgcn_mfma_f32_16x16x32_bf16(af[i], bfr[j], acc[i][j], 0, 0, 0);
  }

  #pragma unroll
  for (int i = 0; i < 4; ++i) {
    #pragma unroll
    for (int j = 0; j < 4; ++j) {
      int row0 = m0 + wr * 64 + i * 16 + lg * 4;
      int col  = n0 + wc * 64 + j * 16 + li;
      float bv = BIAS ? bias[col] : 0.f;
      #pragma unroll
      for (int ii = 0; ii < 4; ++ii) {
        float val = acc[i][j][ii] + bv;
        if (RELU) val = fmaxf(val, 0.f);
        size_t off = (size_t)(row0 + ii) * N + col;
        if (RESID) { val += xres[off]; xres[off] = val; }
        if (OUT == 1) ((ushort*)outp)[off] = f2bf(val);
        if (OUT == 2) ((float*)outp)[off] = val;
      }
    }
  }
}

// ---------------- MFMA causal flash attention, 128-row q-tiles ----------------
// qkv: [NTOK][2304] bf16 (q: col h*64, k: 768+h*64, v: 1536+h*64). o: [NTOK][768].
// 4 waves x 32 q-rows each; K/V staged once per 64-key chunk, amortized 2x vs 64-row tiles.
__global__ __launch_bounds__(256) void attn_kernel(
    const ushort* __restrict__ qkv, ushort* __restrict__ o)
{
  __shared__ ushort Ks[64 * 64];      // [key][dh], swizzled
  __shared__ ushort Vt[64 * 64];      // [dh][key], swizzled
  __shared__ ushort Ps[4][32 * 64];   // per-wave P [qrow 0..31][key], swizzled

  const int tid = threadIdx.x;
  const int lane = tid & 63;
  const int w = tid >> 6;
  const int lg = lane >> 4;
  const int li = lane & 15;

  int bid = blockIdx.x;
  const int qt = bid & 7;             // NT/128 = 8 q-tiles
  const int h = (bid >> 3) % NH;
  const int b = bid / (8 * NH);
  const int q0 = qt * 128 + w * 32;   // this wave's first q row
  const size_t nbase = (size_t)b * NT;
  const int hq = h * NDH;
  const int hk = ND + h * NDH;
  const int hv = 2 * ND + h * NDH;

  s16x8 aq[2][2];
  #pragma unroll
  for (int f = 0; f < 2; ++f)
    #pragma unroll
    for (int c = 0; c < 2; ++c)
      aq[f][c] = *(const s16x8*)&qkv[(nbase + q0 + f * 16 + li) * (3 * ND) + hq + c * 32 + lg * 8];

  float m_r[2][4], l_r[2][4];
  f32x4 oacc[2][4];
  #pragma unroll
  for (int f = 0; f < 2; ++f)
    #pragma unroll
    for (int i = 0; i < 4; ++i) { m_r[f][i] = -1e30f; l_r[f][i] = 0.f; }
  #pragma unroll
  for (int f = 0; f < 2; ++f)
    #pragma unroll
    for (int n = 0; n < 4; ++n) { f32x4 z = {0.f,0.f,0.f,0.f}; oacc[f][n] = z; }

  const float scale = 0.036084391824351615f;  // 768^-0.5 (reference uses D, not DH)

  const int nkc = 2 * qt + 2;
  for (int kc = 0; kc < nkc; ++kc) {
    #pragma unroll
    for (int p = 0; p < 2; ++p) {
      int id2 = p * 256 + tid;
      int key = id2 >> 3, c8 = (id2 & 7) * 8;
      size_t rb = (nbase + kc * 64 + key) * (size_t)(3 * ND);
      u32x4 kvv = *(const u32x4*)&qkv[rb + hk + c8];
      *(u32x4*)&Ks[swz(key, c8)] = kvv;
      u32x4 vvv = *(const u32x4*)&qkv[rb + hv + c8];
      ushort* vp = (ushort*)&vvv;
      #pragma unroll
      for (int j = 0; j < 8; ++j) Vt[swz(c8 + j, key)] = vp[j];
    }
    __syncthreads();
    if (kc * 64 <= q0 + 31) {
      // QK^T: C row = q row (f*16 + lg*4 + i), col = key (kt*16 + li)
      f32x4 s[2][4];
      #pragma unroll
      for (int kt = 0; kt < 4; ++kt) {
        s16x8 bk[2];
        #pragma unroll
        for (int c = 0; c < 2; ++c)
          bk[c] = *(const s16x8*)&Ks[swz(kt * 16 + li, c * 32 + lg * 8)];
        #pragma unroll
        for (int f = 0; f < 2; ++f) {
          f32x4 z = {0.f,0.f,0.f,0.f}; s[f][kt] = z;
          #pragma unroll
          for (int c = 0; c < 2; ++c)
            s[f][kt] = __builtin_amdgcn_mfma_f32_16x16x32_bf16(aq[f][c], bk[c], s[f][kt], 0, 0, 0);
        }
      }
      // online softmax per q row
      #pragma unroll
      for (int f = 0; f < 2; ++f) {
        #pragma unroll
        for (int i = 0; i < 4; ++i) {
          int row = q0 + f * 16 + lg * 4 + i;
          float sv[4]; float mx = -1e30f;
          #pragma unroll
          for (int kt = 0; kt < 4; ++kt) {
            int key = kc * 64 + kt * 16 + li;
            float t = s[f][kt][i] * scale;
            t = (key <= row) ? t : -1e30f;
            sv[kt] = t; mx = fmaxf(mx, t);
          }
          #pragma unroll
          for (int d = 1; d < 16; d <<= 1) mx = fmaxf(mx, __shfl_xor(mx, d));
          float mnew = fmaxf(m_r[f][i], mx);
          float corr = __expf(m_r[f][i] - mnew);
          float ps = 0.f;
          #pragma unroll
          for (int kt = 0; kt < 4; ++kt) {
            float pe = __expf(sv[kt] - mnew);
            ps += pe;
            Ps[w][swz(f * 16 + lg * 4 + i, kt * 16 + li)] = f2bf(pe);
          }
          #pragma unroll
          for (int d = 1; d < 16; d <<= 1) ps += __shfl_xor(ps, d);
          l_r[f][i] = l_r[f][i] * corr + ps;
          m_r[f][i] = mnew;
          #pragma unroll
          for (int n = 0; n < 4; ++n) oacc[f][n][i] *= corr;
        }
      }
      // PV: A = P [qrow][key], B^T = Vt [dh][key]; C row = qrow, col = dh
      #pragma unroll
      for (int c = 0; c < 2; ++c) {
        s16x8 ap[2], bv[4];
        #pragma unroll
        for (int f = 0; f < 2; ++f)
          ap[f] = *(const s16x8*)&Ps[w][swz(f * 16 + li, c * 32 + lg * 8)];
        #pragma unroll
        for (int n = 0; n < 4; ++n)
          bv[n] = *(const s16x8*)&Vt[swz(n * 16 + li, c * 32 + lg * 8)];
        #pragma unroll
        for (int f = 0; f < 2; ++f)
          #pragma unroll
          for (int n = 0; n < 4; ++n)
            oacc[f][n] = __builtin_amdgcn_mfma_f32_16x16x32_bf16(ap[f], bv[n], oacc[f][n], 0, 0, 0);
      }
    }
    __syncthreads();
  }
  #pragma unroll
  for (int f = 0; f < 2; ++f)
    #pragma unroll
    for (int n = 0; n < 4; ++n)
      #pragma unroll
      for (int i = 0; i < 4; ++i) {
        float val = oacc[f][n][i] / l_r[f][i];
        o[(nbase + q0 + f * 16 + lg * 4 + i) * ND + hq + n * 16 + li] = f2bf(val);
      }
}

// ---------------- loss (f32 logits), deterministic two-stage ----------------
__global__ __launch_bounds__(256) void loss_row(
    const float* __restrict__ logits, const int* __restrict__ targets,
    float* __restrict__ rowloss)
{
  int row = blockIdx.x, tid = threadIdx.x;
  const float* lr = logits + (size_t)row * NV;
  const float4* l4 = (const float4*)lr;
  float vals[32];
  float mx = -1e30f;
  #pragma unroll
  for (int p = 0; p < 8; ++p) {
    float4 t = l4[p * 256 + tid];
    vals[p*4+0] = t.x; vals[p*4+1] = t.y; vals[p*4+2] = t.z; vals[p*4+3] = t.w;
    mx = fmaxf(mx, fmaxf(fmaxf(t.x, t.y), fmaxf(t.z, t.w)));
  }
  #pragma unroll
  for (int d = 1; d < 64; d <<= 1) mx = fmaxf(mx, __shfl_xor(mx, d));
  __shared__ float red[4], red2[4];
  int w = tid >> 6, lane = tid & 63;
  if (lane == 0) red[w] = mx;
  __syncthreads();
  mx = fmaxf(fmaxf(red[0], red[1]), fmaxf(red[2], red[3]));
  float sm = 0.f;
  #pragma unroll
  for (int i = 0; i < 32; ++i) sm += __expf(vals[i] - mx);
  #pragma unroll
  for (int d = 1; d < 64; d <<= 1) sm += __shfl_xor(sm, d);
  if (lane == 0) red2[w] = sm;
  __syncthreads();
  if (tid == 0) {
    float total = red2[0] + red2[1] + red2[2] + red2[3];
    float lse = mx + __logf(total);
    rowloss[row] = lse - lr[targets[row]];
  }
}

__global__ __launch_bounds__(256) void loss_reduce(
    const float* __restrict__ rowloss, float* __restrict__ out_loss)
{
  int tid = threadIdx.x;
  float s = 0.f;
  #pragma unroll
  for (int i = 0; i < 32; ++i) s += rowloss[tid + i * 256];
  #pragma unroll
  for (int d = 1; d < 64; d <<= 1) s += __shfl_xor(s, d);
  __shared__ float red[4];
  int w = tid >> 6, lane = tid & 63;
  if (lane == 0) red[w] = s;
  __syncthreads();
  if (tid == 0) {
    float total = red[0] + red[1] + red[2] + red[3];
    out_loss[0] = total * (1.0f / NTOK);
  }
}

// ---------------- launch ----------------
extern "C" void kernel_launch(void* const* d_in, const int* in_sizes, int n_in,
                              void* d_out, int out_size, void* d_ws, size_t ws_size,
                              hipStream_t stream)
{
  const int*   idx     = (const int*)d_in[0];
  const int*   targets = (const int*)d_in[1];
  const float* tok     = (const float*)d_in[2];
  const float* pos     = (const float*)d_in[3];
  const float* ln1g    = (const float*)d_in[4];
  const float* ln1b    = (const float*)d_in[5];
  const float* Wq      = (const float*)d_in[6];
  const float* Wk      = (const float*)d_in[7];
  const float* Wv      = (const float*)d_in[8];
  const float* Wp      = (const float*)d_in[9];
  const float* bp      = (const float*)d_in[10];
  const float* ln2g    = (const float*)d_in[11];
  const float* ln2b    = (const float*)d_in[12];
  const float* W1      = (const float*)d_in[13];
  const float* b1      = (const float*)d_in[14];
  const float* W2      = (const float*)d_in[15];
  const float* b2      = (const float*)d_in[16];
  const float* lnfg    = (const float*)d_in[17];
  const float* lnfb    = (const float*)d_in[18];
  const float* Wlm     = (const float*)d_in[19];
  const float* blm     = (const float*)d_in[20];

  // d_out (f32, 268,435,460 B) doubles as scratch; all dead before final GEMM.
  char* ob = (char*)d_out;
  float*  x    = (float*)ob;
  ushort* qkvb = (ushort*)(ob + 25165824);
  ushort* mid  = (ushort*)(ob + 25165824);
  ushort* qkvT = (ushort*)(ob + 75497472);                  // 6 x [2304][768]
  ushort* wpT  = (ushort*)(ob + 75497472 + 21233664);       // 6 x [768][768]
  ushort* w1T  = (ushort*)(ob + 75497472 + 28311552);       // 6 x [3072][768]
  ushort* w2T  = (ushort*)(ob + 75497472 + 56623104);       // 6 x [768][3072]
  float* logits = (float*)d_out;

  char* ws = (char*)d_ws;
  size_t off = 0;
  auto alloc = [&](size_t bytes) -> void* {
    void* p = ws + off; off += (bytes + 255) & ~(size_t)255; return p;
  };
  ushort* h    = (ushort*)alloc((size_t)NTOK * ND * 2);     // ln out / attn out
  ushort* wlmT = (ushort*)alloc((size_t)ND * NV * 2);       // read during logits GEMM
  float*  rowloss = (float*)alloc((size_t)NTOK * 4);

  embed_kernel<<<NTOK, 192, 0, stream>>>(idx, tok, pos, x);

  const size_t LQKV = (size_t)2304 * ND;
  {
    int tq = NL * NH * ND * NDH;
    transp2<<<(tq + 255) / 256, 256, 0, stream>>>(Wq, qkvT,                 ND, NDH, NH, (size_t)NDH * ND, LQKV, tq);
    transp2<<<(tq + 255) / 256, 256, 0, stream>>>(Wk, qkvT + (size_t)ND*ND, ND, NDH, NH, (size_t)NDH * ND, LQKV, tq);
    transp2<<<(tq + 255) / 256, 256, 0, stream>>>(Wv, qkvT + (size_t)2*ND*ND, ND, NDH, NH, (size_t)NDH * ND, LQKV, tq);
    int tp = NL * ND * ND;
    transp2<<<(tp + 255) / 256, 256, 0, stream>>>(Wp, wpT, ND, ND, 1, 0, (size_t)ND * ND, tp);
    int tf = NL * ND * NFF;
    transp2<<<(tf + 255) / 256, 256, 0, stream>>>(W1, w1T, ND, NFF, 1, 0, (size_t)ND * NFF, tf);
    transp2<<<(tf + 255) / 256, 256, 0, stream>>>(W2, w2T, NFF, ND, 1, 0, (size_t)ND * NFF, tf);
    int tl = ND * NV;
    transp2<<<(tl + 255) / 256, 256, 0, stream>>>(Wlm, wlmT, ND, NV, 1, 0, (size_t)ND * NV, tl);
  }

  dim3 gqkv(2304 / 128, NTOK / 128);   // 18 x 64 = 1152
  dim3 g768(ND / 128, NTOK / 128);     // 6 x 64 = 384
  dim3 gff(NFF / 128, NTOK / 128);     // 24 x 64 = 1536
  dim3 glm(NV / 128, NTOK / 128);      // 64 x 64 = 4096

  for (int l = 0; l < NL; ++l) {
    ln_kernel<<<NTOK, 256, 0, stream>>>(x, ln1g + l * ND, ln1b + l * ND, h);
    gemm_bt<false,false,false,1><<<gqkv, 256, 0, stream>>>(h, qkvT + l * LQKV, nullptr, nullptr, qkvb, NTOK, 2304, ND);
    attn_kernel<<<NB * NH * (NT / 128), 256, 0, stream>>>(qkvb, h);
    gemm_bt<true,false,true,0><<<g768, 256, 0, stream>>>(h, wpT + (size_t)l * ND * ND, bp + l * ND, x, nullptr, NTOK, ND, ND);
    ln_kernel<<<NTOK, 256, 0, stream>>>(x, ln2g + l * ND, ln2b + l * ND, h);
    gemm_bt<true,true,false,1><<<gff, 256, 0, stream>>>(h, w1T + (size_t)l * ND * NFF, b1 + (size_t)l * NFF, nullptr, mid, NTOK, NFF, ND);
    gemm_bt<true,false,true,0><<<g768, 256, 0, stream>>>(mid, w2T + (size_t)l * ND * NFF, b2 + l * ND, x, nullptr, NTOK, ND, NFF);
  }

  ln_kernel<<<NTOK, 256, 0, stream>>>(x, lnfg, lnfb, h);
  gemm_bt<true,false,false,2><<<glm, 256, 0, stream>>>(h, wlmT, blm, nullptr, logits, NTOK, NV, ND);

  loss_row<<<NTOK, 256, 0, stream>>>(logits, targets, rowloss);
  loss_reduce<<<1, 256, 0, stream>>>(rowloss, logits + (size_t)NTOK * NV);
}